// Round 2
// baseline (334.894 us; speedup 1.0000x reference)
//
#include <hip/hip_runtime.h>
#include <hip/hip_bf16.h>

typedef __bf16 bf16x8 __attribute__((ext_vector_type(8)));
typedef __bf16 bf16x4 __attribute__((ext_vector_type(4)));
typedef float  f32x4  __attribute__((ext_vector_type(4)));

#define SEQ  4096
#define NH   16
#define HD   128
#define QBLK 64
#define KVBLK 64

__device__ __forceinline__ bf16x8 cvt_bf16x8(f32x4 a, f32x4 b, float scale) {
    bf16x8 v;
    v[0] = (__bf16)(a[0]*scale); v[1] = (__bf16)(a[1]*scale);
    v[2] = (__bf16)(a[2]*scale); v[3] = (__bf16)(a[3]*scale);
    v[4] = (__bf16)(b[0]*scale); v[5] = (__bf16)(b[1]*scale);
    v[6] = (__bf16)(b[2]*scale); v[7] = (__bf16)(b[3]*scale);
    return v;
}

__global__ __launch_bounds__(256, 2) void fattn_kernel(
    const float* __restrict__ Q, const float* __restrict__ K,
    const float* __restrict__ V, float* __restrict__ O)
{
    // K tile row-major swizzled; V tile transposed swizzled; per-wave P^T (pad 20)
    __shared__ __align__(16) __bf16 ldsK[KVBLK * HD];
    __shared__ __align__(16) __bf16 ldsVT[HD * KVBLK];
    __shared__ __align__(16) __bf16 ldsPT[4][KVBLK * 20];

    const int tid  = threadIdx.x;
    const int lane = tid & 63;
    const int wv   = tid >> 6;
    const int c    = lane & 15;   // col index within 16 (A-row / B-col / C-col)
    const int g    = lane >> 4;   // 16-lane group 0..3

    const int h  = blockIdx.x & (NH - 1);
    const int qb = (int)(gridDim.x >> 4) - 1 - (int)(blockIdx.x >> 4); // heavy first
    const int q0 = qb * QBLK;

    const float scale = 0.08838834764831845f;  // 1/sqrt(128)

    // ---- load Q fragments (16 rows per wave), scale folded in ----
    bf16x8 qf[4];
    {
        const float* qrow = Q + (size_t)(q0 + wv*16 + c) * (NH*HD) + h*HD;
        #pragma unroll
        for (int ks = 0; ks < 4; ++ks) {
            const int d0 = 32*ks + 8*g;
            f32x4 a = *(const f32x4*)(qrow + d0);
            f32x4 b = *(const f32x4*)(qrow + d0 + 4);
            qf[ks] = cvt_bf16x8(a, b, scale);
        }
    }

    f32x4 oacc[8];
    #pragma unroll
    for (int i = 0; i < 8; ++i) { oacc[i][0]=0.f; oacc[i][1]=0.f; oacc[i][2]=0.f; oacc[i][3]=0.f; }
    float mrow[4] = {-1e30f,-1e30f,-1e30f,-1e30f};
    float lrow[4] = {0.f,0.f,0.f,0.f};

    const int nkv = qb + 1;
    for (int kb = 0; kb < nkv; ++kb) {
        const int k0 = kb * KVBLK;

        // ---- stage K tile [64][128] bf16, XOR-swizzled rows ----
        #pragma unroll
        for (int it = 0; it < 4; ++it) {
            const int idx = it*256 + tid;
            const int row = idx >> 4, ch = idx & 15;
            const float* src = K + (size_t)(k0+row)*(NH*HD) + h*HD + ch*8;
            f32x4 a = *(const f32x4*)src;
            f32x4 b = *(const f32x4*)(src + 4);
            const int e = (row*HD + ch*8) ^ ((row & 7) << 3);
            *(bf16x8*)&ldsK[e] = cvt_bf16x8(a, b, 1.0f);
        }
        // ---- stage V^T [128][64] bf16, XOR-swizzled rows (row = d) ----
        {
            const int kk = tid & 63;
            const int dbase = (tid >> 6) * 8;
            const float* src = V + (size_t)(k0+kk)*(NH*HD) + h*HD;
            #pragma unroll
            for (int it = 0; it < 4; ++it) {
                const int d0 = dbase + it*32;
                f32x4 a = *(const f32x4*)(src + d0);
                f32x4 b = *(const f32x4*)(src + d0 + 4);
                float vals[8] = {a[0],a[1],a[2],a[3],b[0],b[1],b[2],b[3]};
                #pragma unroll
                for (int j = 0; j < 8; ++j) {
                    const int e = ((d0+j)*KVBLK + kk) ^ (j << 3); // (d&7)==j here
                    ldsVT[e] = (__bf16)vals[j];
                }
            }
        }
        __syncthreads();

        // ---- QK^T: S[16 q][64 k] per wave ----
        f32x4 s[4];
        #pragma unroll
        for (int t = 0; t < 4; ++t) {
            f32x4 acc = {0.f,0.f,0.f,0.f};
            #pragma unroll
            for (int ks = 0; ks < 4; ++ks) {
                const int row = t*16 + c;
                const int e = (row*HD + 32*ks + 8*g) ^ ((row & 7) << 3);
                bf16x8 bk = *(const bf16x8*)&ldsK[e];
                acc = __builtin_amdgcn_mfma_f32_16x16x32_bf16(qf[ks], bk, acc, 0, 0, 0);
            }
            s[t] = acc;
        }

        // ---- causal mask: only the diagonal block needs it ----
        if (kb == qb) {
            #pragma unroll
            for (int t = 0; t < 4; ++t)
                #pragma unroll
                for (int r = 0; r < 4; ++r) {
                    const int qg = q0 + wv*16 + 4*g + r;
                    const int kg = k0 + t*16 + c;
                    if (kg > qg) s[t][r] = -1e30f;
                }
        }

        // ---- online softmax (wave-parallel, reduce over the 16-lane col group) ----
        float alpha[4];
        #pragma unroll
        for (int r = 0; r < 4; ++r) {
            float m0 = fmaxf(fmaxf(s[0][r], s[1][r]), fmaxf(s[2][r], s[3][r]));
            #pragma unroll
            for (int off = 1; off < 16; off <<= 1)
                m0 = fmaxf(m0, __shfl_xor(m0, off, 64));
            const float mn = fmaxf(mrow[r], m0);
            alpha[r] = __expf(mrow[r] - mn);
            mrow[r] = mn;
        }
        float rs[4] = {0.f,0.f,0.f,0.f};
        #pragma unroll
        for (int t = 0; t < 4; ++t)
            #pragma unroll
            for (int r = 0; r < 4; ++r) {
                const float p = __expf(s[t][r] - mrow[r]);
                s[t][r] = p;
                rs[r] += p;
            }
        #pragma unroll
        for (int r = 0; r < 4; ++r) {
            float x = rs[r];
            #pragma unroll
            for (int off = 1; off < 16; off <<= 1)
                x += __shfl_xor(x, off, 64);
            lrow[r] = lrow[r]*alpha[r] + x;
        }
        #pragma unroll
        for (int dt = 0; dt < 8; ++dt)
            #pragma unroll
            for (int r = 0; r < 4; ++r)
                oacc[dt][r] *= alpha[r];

        // ---- P^T to per-wave LDS: pack 4 q-rows (regs) into one b64 write ----
        #pragma unroll
        for (int t = 0; t < 4; ++t) {
            bf16x4 pv;
            pv[0] = (__bf16)s[t][0]; pv[1] = (__bf16)s[t][1];
            pv[2] = (__bf16)s[t][2]; pv[3] = (__bf16)s[t][3];
            const int e = (t*16 + c)*20 + 4*g;
            *(bf16x4*)&ldsPT[wv][e] = pv;
        }

        // ---- read P as A-fragments (lane: row=c, k=8g+j+32ks) ----
        bf16x8 pa[2];
        #pragma unroll
        for (int ks = 0; ks < 2; ++ks) {
            bf16x8 v;
            #pragma unroll
            for (int j = 0; j < 8; ++j)
                v[j] = ldsPT[wv][(32*ks + 8*g + j)*20 + c];
            pa[ks] = v;
        }

        // ---- PV: O[16 q][128 d] += P · V ----
        #pragma unroll
        for (int dt = 0; dt < 8; ++dt) {
            #pragma unroll
            for (int ks = 0; ks < 2; ++ks) {
                const int dd = dt*16 + c;
                const int e = (dd*KVBLK + 32*ks + 8*g) ^ ((dd & 7) << 3);
                bf16x8 bv = *(const bf16x8*)&ldsVT[e];
                oacc[dt] = __builtin_amdgcn_mfma_f32_16x16x32_bf16(pa[ks], bv, oacc[dt], 0, 0, 0);
            }
        }
        __syncthreads();
    }

    // ---- epilogue: normalize and store fp32 ----
    #pragma unroll
    for (int r = 0; r < 4; ++r) {
        const float inv = 1.0f / lrow[r];
        const int qg = q0 + wv*16 + 4*g + r;
        float* orow = O + (size_t)qg*(NH*HD) + h*HD;
        #pragma unroll
        for (int dt = 0; dt < 8; ++dt)
            orow[dt*16 + c] = oacc[dt][r] * inv;
    }
}

extern "C" void kernel_launch(void* const* d_in, const int* in_sizes, int n_in,
                              void* d_out, int out_size, void* d_ws, size_t ws_size,
                              hipStream_t stream) {
    const float* Q = (const float*)d_in[0];
    const float* K = (const float*)d_in[1];
    const float* V = (const float*)d_in[2];
    float* O = (float*)d_out;
    dim3 grid((SEQ / QBLK) * NH);   // 64 q-tiles x 16 heads = 1024 blocks
    dim3 block(256);
    fattn_kernel<<<grid, block, 0, stream>>>(Q, K, V, O);
}